// Round 14
// baseline (277.620 us; speedup 1.0000x reference)
//
#include <hip/hip_runtime.h>
#include <hip/hip_bf16.h>

#define DIN 128
#define KEIG 4
#define BSH 7
#define BCAP 5120
#define ITEMS 16
#define AVG_D_LOG 3.4965075614664802f
#define BN_EPS 1e-5f

typedef __attribute__((ext_vector_type(8))) short bf16x8;
typedef __attribute__((ext_vector_type(4))) float f32x4;
typedef __attribute__((ext_vector_type(2))) float f32x2;

// async global->LDS, 16B per lane; DST must be wave-uniform, SRC is per-lane.
#define GLD16(SRC, DST) __builtin_amdgcn_global_load_lds(                     \
    (const __attribute__((address_space(1))) unsigned int*)(const void*)(SRC),\
    (__attribute__((address_space(3))) unsigned int*)(void*)(DST), 16, 0, 0)

// float -> bf16 (RNE) raw bits; no NaN inputs in this problem.
static __device__ inline unsigned short f2bf(float f) {
    union { float f; unsigned u; } v; v.f = f;
    unsigned r = v.u + 0x7FFFu + ((v.u >> 16) & 1u);
    return (unsigned short)(r >> 16);
}
static __device__ inline unsigned pack2bf(float lo, float hi) {
    return (unsigned)f2bf(lo) | ((unsigned)f2bf(hi) << 16);
}
static __device__ inline f32x2 up2(unsigned u) {
    f32x2 r;
    r.x = __int_as_float(u << 16);
    r.y = __int_as_float(u & 0xffff0000u);
    return r;
}

// ---------------- prep: h->bf16, W->bf16 STAGED layout, eig0, zero cursors ----------------
// WtS staged layout (bytes): [ks][c][lane][16]  with ks=k>>5, kg=(k>>3)&3, ko=k&7,
//   c = s*8 + kg*2 + (col>>6), lane = col&63.  1KB chunk = what one GLD16 stages.

__global__ void k_prep(const float* __restrict__ h, unsigned* __restrict__ hb,
                       const float* __restrict__ W, unsigned short* __restrict__ Wt,
                       const float* __restrict__ eig, float* __restrict__ eig0,
                       int* __restrict__ cursor, int* __restrict__ bcur,
                       int nPairs, int wTotal, int N, int nbk)
{
    int i = blockIdx.x * 256 + threadIdx.x;
    if (i < nPairs) {
        float2 v = reinterpret_cast<const float2*>(h)[i];
        hb[i] = pack2bf(v.x, v.y);
    }
    if (i < wTotal) {
        int k = i % 384;
        int rest = i / 384;
        int col = rest & 127;
        int s = rest >> 7;
        const int ks = k >> 5, kg = (k >> 3) & 3, ko = k & 7;
        const int c = s * 8 + kg * 2 + (col >> 6);
        const int lane = col & 63;
        const size_t idx = (size_t)ks * 12288 + c * 512 + lane * 8 + ko;  // bf16 units
        Wt[idx] = f2bf(W[(s * 384 + k) * 128 + col]);
    }
    if (i < N) {
        eig0[i] = eig[(size_t)i * KEIG];
        cursor[i] = 0;
    }
    if (i < nbk) bcur[i] = 0;
}

// ---------------- pass 1: bucket by dst>>7 with block-bulk reservation ----------------

__global__ void k_bucket(const int* __restrict__ src, const int* __restrict__ dst,
                         const float* __restrict__ eig0, int* __restrict__ bcur,
                         uint2* __restrict__ stag, int E, int nbk)
{
    __shared__ int lcnt[512];
    __shared__ int lbase[512];
    const int t = threadIdx.x;
    for (int b = t; b < nbk; b += 256) lcnt[b] = 0;
    __syncthreads();

    const int e0 = blockIdx.x * (256 * ITEMS);
    int   bky[ITEMS];
    int   rnk[ITEMS];
    uint2 rec[ITEMS];
#pragma unroll
    for (int k = 0; k < ITEMS; ++k) {
        const int e = e0 + t + k * 256;
        if (e < E) {
            const int s = src[e], d = dst[e];
            const float w = fabsf(eig0[s] - eig0[d]);
            rec[k] = make_uint2(((unsigned)f2bf(w) << 16) | (unsigned)s, (unsigned)d);
            bky[k] = d >> BSH;
            rnk[k] = atomicAdd(&lcnt[bky[k]], 1);
        } else bky[k] = -1;
    }
    __syncthreads();
    for (int b = t; b < nbk; b += 256) {
        const int c = lcnt[b];
        lbase[b] = c ? atomicAdd(&bcur[b], c) : 0;
    }
    __syncthreads();
#pragma unroll
    for (int k = 0; k < ITEMS; ++k) {
        if (bky[k] >= 0) {
            const int pos = lbase[bky[k]] + rnk[k];
            if (pos < BCAP) stag[(size_t)bky[k] * BCAP + pos] = rec[k];
        }
    }
}

// ---------------- pass 2: group bucket by dst in LDS; emit packed CSR + offcnt ----------------

__global__ void k_group(const int* __restrict__ bcur, const uint2* __restrict__ stag,
                        unsigned* __restrict__ final_, int2* __restrict__ offcnt, int N)
{
    __shared__ uint2 sst[BCAP];
    __shared__ int hcnt[128];
    __shared__ int sbuf[2][128];
    const int b = blockIdx.x;
    const int t = threadIdx.x;
    const int cb = min(bcur[b], BCAP);

    for (int i = t; i < cb; i += 256) sst[i] = stag[(size_t)b * BCAP + i];
    if (t < 128) hcnt[t] = 0;
    __syncthreads();

    int dl[(BCAP + 255) / 256];
    int rk[(BCAP + 255) / 256];
    int nit = 0;
    for (int i = t; i < cb; i += 256) {
        const int d_loc = sst[i].y & 127;
        dl[nit] = d_loc;
        rk[nit] = atomicAdd(&hcnt[d_loc], 1);
        ++nit;
    }
    __syncthreads();

    int cur = 0;
    if (t < 128) sbuf[0][t] = hcnt[t];
    __syncthreads();
    for (int d = 1; d < 128; d <<= 1) {
        if (t < 128) {
            int x = sbuf[cur][t];
            if (t >= d) x += sbuf[cur][t - d];
            sbuf[cur ^ 1][t] = x;
        }
        cur ^= 1;
        __syncthreads();
    }
    const int exb = cur ^ 1;
    if (t < 128) sbuf[exb][t] = sbuf[cur][t] - hcnt[t];   // exclusive
    __syncthreads();

    if (t < 128) {
        const int dg = (b << BSH) + t;
        if (dg < N) offcnt[dg] = make_int2(b * BCAP + sbuf[exb][t], hcnt[t]);
    }
    nit = 0;
    for (int i = t; i < cb; i += 256) {
        final_[(size_t)b * BCAP + sbuf[exb][dl[nit]] + rk[nit]] = sst[i].x;
        ++nit;
    }
}

// ---------------- CSR fallback path (N >= 65536 or small ws) ----------------

__global__ void k_hist(const int* __restrict__ dst, int* __restrict__ counts, int E) {
    int e = blockIdx.x * 256 + threadIdx.x;
    if (e < E) atomicAdd(&counts[dst[e]], 1);
}

__global__ void k_part(const int* __restrict__ counts, int* __restrict__ part, int N) {
    __shared__ int red[4];
    const int t = threadIdx.x;
    const int i = blockIdx.x * 256 + t;
    int v = (i < N) ? counts[i] : 0;
    for (int d = 32; d >= 1; d >>= 1) v += __shfl_down(v, d, 64);
    if ((t & 63) == 0) red[t >> 6] = v;
    __syncthreads();
    if (t == 0) part[blockIdx.x] = red[0] + red[1] + red[2] + red[3];
}

__global__ void k_scan1(const int* __restrict__ part, int* __restrict__ partoff,
                        int* __restrict__ total_out, int NB) {
    __shared__ int buf[2][256];
    const int t = threadIdx.x;
    int v = (t < NB) ? part[t] : 0;
    buf[0][t] = v;
    __syncthreads();
    int cur = 0;
    for (int d = 1; d < 256; d <<= 1) {
        int x = buf[cur][t];
        if (t >= d) x += buf[cur][t - d];
        buf[cur ^ 1][t] = x;
        cur ^= 1;
        __syncthreads();
    }
    if (t < NB) partoff[t] = buf[cur][t] - v;
    if (t == 255) *total_out = buf[cur][255];
}

__global__ void k_off(const int* __restrict__ counts, const int* __restrict__ partoff,
                      int* __restrict__ offsets, int* __restrict__ cursor, int N) {
    __shared__ int buf[2][256];
    const int t = threadIdx.x;
    const int i = blockIdx.x * 256 + t;
    int v = (i < N) ? counts[i] : 0;
    buf[0][t] = v;
    __syncthreads();
    int cur = 0;
    for (int d = 1; d < 256; d <<= 1) {
        int x = buf[cur][t];
        if (t >= d) x += buf[cur][t - d];
        buf[cur ^ 1][t] = x;
        cur ^= 1;
        __syncthreads();
    }
    if (i < N) {
        int excl = partoff[blockIdx.x] + buf[cur][t] - v;
        offsets[i] = excl;
        cursor[i]  = excl;
    }
}

__global__ void k_fill_csr(const int* __restrict__ src, const int* __restrict__ dst,
                           const float* __restrict__ eig0, int* __restrict__ cursor,
                           int2* __restrict__ sedge, int E)
{
    int e = blockIdx.x * 256 + threadIdx.x;
    if (e < E) {
        int s = src[e], d = dst[e];
        float w = fabsf(eig0[s] - eig0[d]);
        int pos = atomicAdd(&cursor[d], 1);
        sedge[pos] = make_int2(s, __float_as_int(w));
    }
}

// ---------------- k_agg: gather + aggregate; writes STAGED agg layout ----------------
// aggS (bytes): [mt][ks][kg][row][16]  mt=n>>6, row=n&63; lane l16 part p:
//   ks = p*4 + (l16>>2), kg = l16&3.
// Full 8-edge batches: 4 edge-pairs, v_max3 fusion, no per-edge predicates.

template<bool PACKED>
__launch_bounds__(256, 4)
__global__ void k_agg(const unsigned* __restrict__ hb,
                      const int2* __restrict__ offcnt, const int* __restrict__ offsets,
                      const unsigned* __restrict__ upk, const int2* __restrict__ sedge,
                      unsigned short* __restrict__ agg, float2* __restrict__ scal, int N)
{
    const int tid = threadIdx.x;
    const int qid = tid >> 4;       // 0..15
    const int l16 = tid & 15;
    const int n = blockIdx.x * 16 + qid;
    if (n >= N) return;

    int e0, cnt;
    if (PACKED) { const int2 oc = offcnt[n]; e0 = oc.x; cnt = oc.y; }
    else        { e0 = offsets[n]; cnt = offsets[n + 1] - e0; }

    const uint4* __restrict__ hb4 = reinterpret_cast<const uint4*>(hb);

    f32x2 s2[4], m2[4], d2[4];
    float wsum = 0.f;
#pragma unroll
    for (int f = 0; f < 4; ++f) {
        s2[f] = (f32x2){0.f, 0.f};
        m2[f] = (f32x2){-INFINITY, -INFINITY};
        d2[f] = (f32x2){0.f, 0.f};
    }
    const int clampi = (cnt > 0) ? cnt - 1 : 0;

    uint4 bufA[8], bufB[8];
    float wvA[8], wvB[8];

#define STAGE(BUF, WV, BASE) do {                                        \
    _Pragma("unroll")                                                    \
    for (int j = 0; j < 8; ++j) {                                        \
        int ci = (BASE) + j; ci = ci < clampi ? ci : clampi;             \
        unsigned sidx;                                                   \
        if (PACKED) {                                                    \
            const unsigned u = upk[e0 + ci];                             \
            WV[j] = __int_as_float(u & 0xffff0000u);                     \
            sidx = (u & 0xffffu) << 4;                                   \
        } else {                                                         \
            const int2 v = sedge[e0 + ci];                               \
            WV[j] = __int_as_float(v.y);                                 \
            sidx = ((unsigned)v.x) << 4;                                 \
        }                                                                \
        BUF[j] = hb4[sidx | (unsigned)l16];                              \
    }                                                                    \
} while (0)

// full batch: 4 edge-pairs, pairwise sum/wsum, 3-input max (v_max3 fusion)
#define ACCUM_FULL(BUF, WV) do {                                         \
    _Pragma("unroll")                                                    \
    for (int jp = 0; jp < 4; ++jp) {                                     \
        const float wa = WV[2 * jp], wb = WV[2 * jp + 1];                \
        const f32x2 wa2 = (f32x2){wa, wa}, wb2 = (f32x2){wb, wb};        \
        const f32x2 a0 = up2(BUF[2 * jp].x),     a1 = up2(BUF[2 * jp].y); \
        const f32x2 a2 = up2(BUF[2 * jp].z),     a3 = up2(BUF[2 * jp].w); \
        const f32x2 b0 = up2(BUF[2 * jp + 1].x), b1 = up2(BUF[2 * jp + 1].y); \
        const f32x2 b2 = up2(BUF[2 * jp + 1].z), b3 = up2(BUF[2 * jp + 1].w); \
        s2[0] += a0 + b0; s2[1] += a1 + b1;                              \
        s2[2] += a2 + b2; s2[3] += a3 + b3;                              \
        m2[0].x = fmaxf(fmaxf(m2[0].x, a0.x), b0.x);                     \
        m2[0].y = fmaxf(fmaxf(m2[0].y, a0.y), b0.y);                     \
        m2[1].x = fmaxf(fmaxf(m2[1].x, a1.x), b1.x);                     \
        m2[1].y = fmaxf(fmaxf(m2[1].y, a1.y), b1.y);                     \
        m2[2].x = fmaxf(fmaxf(m2[2].x, a2.x), b2.x);                     \
        m2[2].y = fmaxf(fmaxf(m2[2].y, a2.y), b2.y);                     \
        m2[3].x = fmaxf(fmaxf(m2[3].x, a3.x), b3.x);                     \
        m2[3].y = fmaxf(fmaxf(m2[3].y, a3.y), b3.y);                     \
        d2[0] += a0 * wa2; d2[0] += b0 * wb2;                            \
        d2[1] += a1 * wa2; d2[1] += b1 * wb2;                            \
        d2[2] += a2 * wa2; d2[2] += b2 * wb2;                            \
        d2[3] += a3 * wa2; d2[3] += b3 * wb2;                            \
        wsum += wa + wb;                                                 \
    }                                                                    \
} while (0)

#define ACCUM_TAIL(BUF, WV, BASE) do {                                   \
    _Pragma("unroll")                                                    \
    for (int j = 0; j < 8; ++j) {                                        \
        if ((BASE) + j < cnt) {                                          \
            const float wj = WV[j];                                      \
            const f32x2 wj2 = (f32x2){wj, wj};                           \
            const f32x2 p0 = up2(BUF[j].x), p1 = up2(BUF[j].y);          \
            const f32x2 p2 = up2(BUF[j].z), p3 = up2(BUF[j].w);          \
            s2[0] += p0; s2[1] += p1; s2[2] += p2; s2[3] += p3;          \
            m2[0].x = fmaxf(m2[0].x, p0.x); m2[0].y = fmaxf(m2[0].y, p0.y); \
            m2[1].x = fmaxf(m2[1].x, p1.x); m2[1].y = fmaxf(m2[1].y, p1.y); \
            m2[2].x = fmaxf(m2[2].x, p2.x); m2[2].y = fmaxf(m2[2].y, p2.y); \
            m2[3].x = fmaxf(m2[3].x, p3.x); m2[3].y = fmaxf(m2[3].y, p3.y); \
            d2[0] += p0 * wj2; d2[1] += p1 * wj2;                        \
            d2[2] += p2 * wj2; d2[3] += p3 * wj2;                        \
            wsum += wj;                                                  \
        }                                                                \
    }                                                                    \
} while (0)

    if (cnt > 0) {
        STAGE(bufA, wvA, 0);
        for (int base = 0; base < cnt; base += 16) {
            const bool haveB = (base + 8) < cnt;
            if (haveB) STAGE(bufB, wvB, base + 8);
            if (base + 8 <= cnt) ACCUM_FULL(bufA, wvA);
            else                 ACCUM_TAIL(bufA, wvA, base);
            if (base + 16 < cnt) STAGE(bufA, wvA, base + 16);
            if (haveB) {
                if (base + 16 <= cnt) ACCUM_FULL(bufB, wvB);
                else                  ACCUM_TAIL(bufB, wvB, base + 8);
            }
        }
    }
#undef STAGE
#undef ACCUM_FULL
#undef ACCUM_TAIL

    const float degf = (float)cnt;
    const float inv  = 1.0f / fmaxf(degf, 1.0f);
    const float dinv = 1.0f / (wsum + 1e-30f);
    const bool nz = (cnt > 0);
    uint4 pm, px, pd;
    pm.x = pack2bf(s2[0].x * inv, s2[0].y * inv);
    pm.y = pack2bf(s2[1].x * inv, s2[1].y * inv);
    pm.z = pack2bf(s2[2].x * inv, s2[2].y * inv);
    pm.w = pack2bf(s2[3].x * inv, s2[3].y * inv);
    px.x = pack2bf(nz ? m2[0].x : 0.f, nz ? m2[0].y : 0.f);
    px.y = pack2bf(nz ? m2[1].x : 0.f, nz ? m2[1].y : 0.f);
    px.z = pack2bf(nz ? m2[2].x : 0.f, nz ? m2[2].y : 0.f);
    px.w = pack2bf(nz ? m2[3].x : 0.f, nz ? m2[3].y : 0.f);
    pd.x = pack2bf(d2[0].x * dinv, d2[0].y * dinv);
    pd.y = pack2bf(d2[1].x * dinv, d2[1].y * dinv);
    pd.z = pack2bf(d2[2].x * dinv, d2[2].y * dinv);
    pd.w = pack2bf(d2[3].x * dinv, d2[3].y * dinv);

    uint4* aggv = reinterpret_cast<uint4*>(agg);
    const int mt = n >> 6, row = n & 63;
    const size_t b4 = (size_t)mt * 3072 + (size_t)(l16 & 3) * 64 + row;
    const int kshi = l16 >> 2;                    // ks = p*4 + kshi
    aggv[b4 + (size_t)(0 * 4 + kshi) * 256] = pm; // part 0 (mean)
    aggv[b4 + (size_t)(1 * 4 + kshi) * 256] = px; // part 1 (max)
    aggv[b4 + (size_t)(2 * 4 + kshi) * 256] = pd; // part 2 (dir)
    if (l16 == 0) {
        const float logD = logf(degf + 1.0f);
        scal[n] = make_float2(logD / AVG_D_LOG, AVG_D_LOG / fmaxf(logD, 1e-6f));
    }
}

// ---------------- k_mm: small-LDS single-buffer MFMA + coalesced epilogue (M=64) ----------------
// 33.8KB LDS -> 4 blocks/CU; two barriers per K-step; inter-block overlap hides the
// staged-load latency (m114). Staged layouts keep every GLD16 source contiguous 1KB.

__launch_bounds__(256)
__global__ void k_mm(const unsigned short* __restrict__ agg, const float2* __restrict__ scal,
                     const float* __restrict__ h, const float* __restrict__ snorm,
                     const float* __restrict__ bvec, const float* __restrict__ gam,
                     const float* __restrict__ bet, const float* __restrict__ bmean,
                     const float* __restrict__ bvar, const unsigned short* __restrict__ Wt,
                     float* __restrict__ out, int N)
{
    __shared__ char smem[33792];                 // max(As 4K + Bs 24K, outS 64*132*4)
    unsigned short* As = (unsigned short*)smem;
    unsigned short* Bs = (unsigned short*)(smem + 4096);
    float* outS = (float*)smem;

    const int tid  = threadIdx.x;
    const int wave = tid >> 6;
    const int lane = tid & 63;
    const int r16  = lane & 15;
    const int kgrp = lane >> 4;
    const int node0 = blockIdx.x * 64;
    const int cb = wave * 32;

    const char* aggbase = (const char*)agg + (size_t)blockIdx.x * 49152;
    const char* wtbase  = (const char*)Wt;

    auto stage = [&](int ks) {
        {
            char* dst = (char*)As + (size_t)wave * 1024;
            const char* src = aggbase + (size_t)ks * 4096 + wave * 1024 + lane * 16;
            GLD16(src, dst);
        }
#pragma unroll
        for (int i = 0; i < 6; ++i) {
            const int c = wave * 6 + i;
            char* dst = (char*)Bs + (size_t)c * 1024;
            const char* src = wtbase + (size_t)ks * 24576 + (size_t)c * 1024 + lane * 16;
            GLD16(src, dst);
        }
    };

    f32x4 acc[4][2][3];
#pragma unroll
    for (int m = 0; m < 4; ++m)
#pragma unroll
        for (int ct = 0; ct < 2; ++ct)
#pragma unroll
            for (int sv = 0; sv < 3; ++sv)
                acc[m][ct][sv] = (f32x4){0.f, 0.f, 0.f, 0.f};

    for (int ks = 0; ks < 12; ++ks) {
        if (ks) __syncthreads();            // prev step's LDS reads done
        stage(ks);
        __syncthreads();                    // vmcnt drained: staged data ready

        bf16x8 a[4], b[6];
#pragma unroll
        for (int m = 0; m < 4; ++m)
            a[m] = *reinterpret_cast<const bf16x8*>(
                &As[((size_t)kgrp * 64 + m * 16 + r16) * 8]);
#pragma unroll
        for (int sv = 0; sv < 3; ++sv)
#pragma unroll
            for (int ct = 0; ct < 2; ++ct)
                b[sv * 2 + ct] = *reinterpret_cast<const bf16x8*>(
                    &Bs[(((size_t)sv * 4 + kgrp) * 128 + cb + ct * 16 + r16) * 8]);
#pragma unroll
        for (int sv = 0; sv < 3; ++sv)
#pragma unroll
            for (int ct = 0; ct < 2; ++ct)
#pragma unroll
                for (int m = 0; m < 4; ++m)
                    acc[m][ct][sv] = __builtin_amdgcn_mfma_f32_16x16x32_bf16(
                        a[m], b[sv * 2 + ct], acc[m][ct][sv], 0, 0, 0);
    }

    // ---- epilogue phase 1: y (through relu) -> LDS ----
    __syncthreads();                        // all waves done reading As/Bs
#pragma unroll
    for (int ct = 0; ct < 2; ++ct) {
        const int col = cb + ct * 16 + r16;
        const float bc  = bvec[col];
        const float mc  = bmean[col];
        const float rs  = rsqrtf(bvar[col] + BN_EPS);
        const float gc  = gam[col];
        const float bec = bet[col];
#pragma unroll
        for (int m = 0; m < 4; ++m) {
#pragma unroll
            for (int r = 0; r < 4; ++r) {
                const int row = m * 16 + kgrp * 4 + r;
                const int n  = node0 + row;
                float sn = 0.f; float2 sc = make_float2(0.f, 0.f);
                if (n < N) { sn = snorm[n]; sc = scal[n]; }
                float v = acc[m][ct][0][r] + sc.x * acc[m][ct][1][r]
                                           + sc.y * acc[m][ct][2][r];
                float y = (v + bc) * sn;
                y = (y - mc) * rs * gc + bec;
                y = fmaxf(y, 0.f);
                outS[row * 132 + col] = y;
            }
        }
    }
    __syncthreads();

    // ---- epilogue phase 2: coalesced residual + store (float4) ----
    const int rows = (N - node0 < 64) ? (N - node0) : 64;
#pragma unroll
    for (int it = 0; it < 8; ++it) {
        const int idx = it * 256 + tid;     // [0, 2048) float4 slots
        const int row = idx >> 5;
        const int c4  = idx & 31;
        if (row < rows) {
            const float4 hv = *reinterpret_cast<const float4*>(
                &h[(size_t)(node0 + row) * 128 + c4 * 4]);
            float4 yv = *reinterpret_cast<const float4*>(&outS[row * 132 + c4 * 4]);
            yv.x += hv.x; yv.y += hv.y; yv.z += hv.z; yv.w += hv.w;
            *reinterpret_cast<float4*>(&out[(size_t)(node0 + row) * 128 + c4 * 4]) = yv;
        }
    }
}

// ---------------- launch ----------------

extern "C" void kernel_launch(void* const* d_in, const int* in_sizes, int n_in,
                              void* d_out, int out_size, void* d_ws, size_t ws_size,
                              hipStream_t stream)
{
    const float* h     = (const float*)d_in[0];
    const float* eig   = (const float*)d_in[1];
    const float* snorm = (const float*)d_in[2];
    const float* W     = (const float*)d_in[3];
    const float* bvec  = (const float*)d_in[4];
    const float* gam   = (const float*)d_in[5];
    const float* bet   = (const float*)d_in[6];
    const float* bmean = (const float*)d_in[7];
    const float* bvar  = (const float*)d_in[8];
    const int*   esrc  = (const int*)d_in[9];
    const int*   edst  = (const int*)d_in[10];
    float* out = (float*)d_out;

    const int N = in_sizes[0] / DIN;
    const int E = in_sizes[9];
    const int NB = (N + 255) / 256;
    const int nPairs = N * DIN / 2;
    const int wTotal = 3 * 128 * 384;
    const int nbk = (N + 127) >> BSH;
    const int N64 = (N + 63) / 64;
    (void)ws_size; (void)n_in; (void)out_size;

    char* base = (char*)d_ws;
    size_t o = 0;
    auto take = [&](size_t bytes) {
        char* p = base + o;
        o = (o + bytes + 255) & ~(size_t)255;
        return p;
    };
    // common scratch
    unsigned* hb       = (unsigned*)take((size_t)nPairs * 4);
    unsigned short* Wt = (unsigned short*)take((size_t)wTotal * 2);
    float* eig0        = (float*)take((size_t)N * 4);
    int* cursor        = (int*)take((size_t)(N + 1) * 4);
    float2* scal       = (float2*)take((size_t)N * 8);

    const size_t agg_bytes  = (size_t)N64 * 49152;   // staged [mt][ks][kg][row][16]
    const size_t stag_bytes = (size_t)nbk * BCAP * 8;
    const size_t shared_bytes = agg_bytes > stag_bytes ? agg_bytes : stag_bytes;

    const size_t bucket_bytes = (size_t)nbk * BCAP * 4
                              + (size_t)N * 8
                              + (size_t)nbk * 4
                              + shared_bytes + 8192;
    const bool bucketOK = (N <= 65536) && (nbk <= 512) && ((o + bucket_bytes) <= ws_size);

    const int gridPrep = (nPairs + 255) / 256;
    const int gridE    = (E + 255) / 256;
    const int gridB    = (E + 256 * ITEMS - 1) / (256 * ITEMS);
    const int gridN16  = (N + 15) / 16;

    if (bucketOK) {
        unsigned* fin   = (unsigned*)take((size_t)nbk * BCAP * 4);
        int2* offcnt    = (int2*)take((size_t)N * 8);
        int* bcur       = (int*)take((size_t)nbk * 4);
        char* shared    = take(shared_bytes);
        uint2* stag     = (uint2*)shared;                 // dead after k_group
        unsigned short* agg = (unsigned short*)shared;    // written by k_agg

        k_prep<<<gridPrep, 256, 0, stream>>>(h, hb, W, Wt, eig, eig0, cursor, bcur,
                                             nPairs, wTotal, N, nbk);
        k_bucket<<<gridB, 256, 0, stream>>>(esrc, edst, eig0, bcur, stag, E, nbk);
        k_group<<<nbk, 256, 0, stream>>>(bcur, stag, fin, offcnt, N);
        k_agg<true><<<gridN16, 256, 0, stream>>>(hb, offcnt, nullptr, fin, nullptr,
                                                 agg, scal, N);
        k_mm<<<N64, 256, 0, stream>>>(agg, scal, h, snorm, bvec, gam, bet, bmean, bvar,
                                      Wt, out, N);
    } else {
        int* counts  = (int*)take((size_t)(N + 1) * 4);
        int* offsets = (int*)take((size_t)(N + 1) * 4);
        int2* sedge  = (int2*)take((size_t)(E + 16) * 8);
        int* part    = (int*)take((size_t)NB * 4);
        int* partoff = (int*)take((size_t)NB * 4);
        int* bcur    = (int*)take(4096);
        unsigned short* agg = (unsigned short*)take(agg_bytes);

        k_prep<<<gridPrep, 256, 0, stream>>>(h, hb, W, Wt, eig, eig0, counts, bcur,
                                             nPairs, wTotal, N, 1);
        k_hist<<<gridE, 256, 0, stream>>>(edst, counts, E);
        k_part<<<NB, 256, 0, stream>>>(counts, part, N);
        k_scan1<<<1, 256, 0, stream>>>(part, partoff, &offsets[N], NB);
        k_off<<<NB, 256, 0, stream>>>(counts, partoff, offsets, cursor, N);
        k_fill_csr<<<gridE, 256, 0, stream>>>(esrc, edst, eig0, cursor, sedge, E);
        k_agg<false><<<gridN16, 256, 0, stream>>>(hb, nullptr, offsets, nullptr, sedge,
                                                  agg, scal, N);
        k_mm<<<N64, 256, 0, stream>>>(agg, scal, h, snorm, bvec, gam, bet, bmean, bvar,
                                      Wt, out, N);
    }
}

// Round 15
// 150.064 us; speedup vs baseline: 1.8500x; 1.8500x over previous
//
#include <hip/hip_runtime.h>
#include <hip/hip_bf16.h>

#define DIN 128
#define KEIG 4
#define BSH 7
#define BCAP 5120
#define ITEMS 16
#define AVG_D_LOG 3.4965075614664802f
#define BN_EPS 1e-5f

typedef __attribute__((ext_vector_type(8))) short bf16x8;
typedef __attribute__((ext_vector_type(4))) float f32x4;
typedef __attribute__((ext_vector_type(2))) float f32x2;

// async global->LDS, 16B per lane; DST must be wave-uniform, SRC is per-lane.
#define GLD16(SRC, DST) __builtin_amdgcn_global_load_lds(                     \
    (const __attribute__((address_space(1))) unsigned int*)(const void*)(SRC),\
    (__attribute__((address_space(3))) unsigned int*)(void*)(DST), 16, 0, 0)

// float -> bf16 (RNE) raw bits; no NaN inputs in this problem.
static __device__ inline unsigned short f2bf(float f) {
    union { float f; unsigned u; } v; v.f = f;
    unsigned r = v.u + 0x7FFFu + ((v.u >> 16) & 1u);
    return (unsigned short)(r >> 16);
}
static __device__ inline unsigned pack2bf(float lo, float hi) {
    return (unsigned)f2bf(lo) | ((unsigned)f2bf(hi) << 16);
}
static __device__ inline f32x2 up2(unsigned u) {
    f32x2 r;
    r.x = __int_as_float(u << 16);
    r.y = __int_as_float(u & 0xffff0000u);
    return r;
}

// ---------------- prep: h->bf16, W->bf16 STAGED layout, eig0, zero cursors ----------------
// WtS staged layout (bytes): [ks][c][lane][16]  with ks=k>>5, kg=(k>>3)&3, ko=k&7,
//   c = s*8 + kg*2 + (col>>6), lane = col&63.  1KB chunk = what one GLD16 stages.

__global__ void k_prep(const float* __restrict__ h, unsigned* __restrict__ hb,
                       const float* __restrict__ W, unsigned short* __restrict__ Wt,
                       const float* __restrict__ eig, float* __restrict__ eig0,
                       int* __restrict__ cursor, int* __restrict__ bcur,
                       int nPairs, int wTotal, int N, int nbk)
{
    int i = blockIdx.x * 256 + threadIdx.x;
    if (i < nPairs) {
        float2 v = reinterpret_cast<const float2*>(h)[i];
        hb[i] = pack2bf(v.x, v.y);
    }
    if (i < wTotal) {
        int k = i % 384;
        int rest = i / 384;
        int col = rest & 127;
        int s = rest >> 7;
        const int ks = k >> 5, kg = (k >> 3) & 3, ko = k & 7;
        const int c = s * 8 + kg * 2 + (col >> 6);
        const int lane = col & 63;
        const size_t idx = (size_t)ks * 12288 + c * 512 + lane * 8 + ko;  // bf16 units
        Wt[idx] = f2bf(W[(s * 384 + k) * 128 + col]);
    }
    if (i < N) {
        eig0[i] = eig[(size_t)i * KEIG];
        cursor[i] = 0;
    }
    if (i < nbk) bcur[i] = 0;
}

// ---------------- pass 1: bucket by dst>>7 with block-bulk reservation ----------------

__global__ void k_bucket(const int* __restrict__ src, const int* __restrict__ dst,
                         const float* __restrict__ eig0, int* __restrict__ bcur,
                         uint2* __restrict__ stag, int E, int nbk)
{
    __shared__ int lcnt[512];
    __shared__ int lbase[512];
    const int t = threadIdx.x;
    for (int b = t; b < nbk; b += 256) lcnt[b] = 0;
    __syncthreads();

    const int e0 = blockIdx.x * (256 * ITEMS);
    int   bky[ITEMS];
    int   rnk[ITEMS];
    uint2 rec[ITEMS];
#pragma unroll
    for (int k = 0; k < ITEMS; ++k) {
        const int e = e0 + t + k * 256;
        if (e < E) {
            const int s = src[e], d = dst[e];
            const float w = fabsf(eig0[s] - eig0[d]);
            rec[k] = make_uint2(((unsigned)f2bf(w) << 16) | (unsigned)s, (unsigned)d);
            bky[k] = d >> BSH;
            rnk[k] = atomicAdd(&lcnt[bky[k]], 1);
        } else bky[k] = -1;
    }
    __syncthreads();
    for (int b = t; b < nbk; b += 256) {
        const int c = lcnt[b];
        lbase[b] = c ? atomicAdd(&bcur[b], c) : 0;
    }
    __syncthreads();
#pragma unroll
    for (int k = 0; k < ITEMS; ++k) {
        if (bky[k] >= 0) {
            const int pos = lbase[bky[k]] + rnk[k];
            if (pos < BCAP) stag[(size_t)bky[k] * BCAP + pos] = rec[k];
        }
    }
}

// ---------------- pass 2: group bucket by dst in LDS; emit packed CSR + offcnt ----------------

__global__ void k_group(const int* __restrict__ bcur, const uint2* __restrict__ stag,
                        unsigned* __restrict__ final_, int2* __restrict__ offcnt, int N)
{
    __shared__ uint2 sst[BCAP];
    __shared__ int hcnt[128];
    __shared__ int sbuf[2][128];
    const int b = blockIdx.x;
    const int t = threadIdx.x;
    const int cb = min(bcur[b], BCAP);

    for (int i = t; i < cb; i += 256) sst[i] = stag[(size_t)b * BCAP + i];
    if (t < 128) hcnt[t] = 0;
    __syncthreads();

    int dl[(BCAP + 255) / 256];
    int rk[(BCAP + 255) / 256];
    int nit = 0;
    for (int i = t; i < cb; i += 256) {
        const int d_loc = sst[i].y & 127;
        dl[nit] = d_loc;
        rk[nit] = atomicAdd(&hcnt[d_loc], 1);
        ++nit;
    }
    __syncthreads();

    int cur = 0;
    if (t < 128) sbuf[0][t] = hcnt[t];
    __syncthreads();
    for (int d = 1; d < 128; d <<= 1) {
        if (t < 128) {
            int x = sbuf[cur][t];
            if (t >= d) x += sbuf[cur][t - d];
            sbuf[cur ^ 1][t] = x;
        }
        cur ^= 1;
        __syncthreads();
    }
    const int exb = cur ^ 1;
    if (t < 128) sbuf[exb][t] = sbuf[cur][t] - hcnt[t];   // exclusive
    __syncthreads();

    if (t < 128) {
        const int dg = (b << BSH) + t;
        if (dg < N) offcnt[dg] = make_int2(b * BCAP + sbuf[exb][t], hcnt[t]);
    }
    nit = 0;
    for (int i = t; i < cb; i += 256) {
        final_[(size_t)b * BCAP + sbuf[exb][dl[nit]] + rk[nit]] = sst[i].x;
        ++nit;
    }
}

// ---------------- CSR fallback path (N >= 65536 or small ws) ----------------

__global__ void k_hist(const int* __restrict__ dst, int* __restrict__ counts, int E) {
    int e = blockIdx.x * 256 + threadIdx.x;
    if (e < E) atomicAdd(&counts[dst[e]], 1);
}

__global__ void k_part(const int* __restrict__ counts, int* __restrict__ part, int N) {
    __shared__ int red[4];
    const int t = threadIdx.x;
    const int i = blockIdx.x * 256 + t;
    int v = (i < N) ? counts[i] : 0;
    for (int d = 32; d >= 1; d >>= 1) v += __shfl_down(v, d, 64);
    if ((t & 63) == 0) red[t >> 6] = v;
    __syncthreads();
    if (t == 0) part[blockIdx.x] = red[0] + red[1] + red[2] + red[3];
}

__global__ void k_scan1(const int* __restrict__ part, int* __restrict__ partoff,
                        int* __restrict__ total_out, int NB) {
    __shared__ int buf[2][256];
    const int t = threadIdx.x;
    int v = (t < NB) ? part[t] : 0;
    buf[0][t] = v;
    __syncthreads();
    int cur = 0;
    for (int d = 1; d < 256; d <<= 1) {
        int x = buf[cur][t];
        if (t >= d) x += buf[cur][t - d];
        buf[cur ^ 1][t] = x;
        cur ^= 1;
        __syncthreads();
    }
    if (t < NB) partoff[t] = buf[cur][t] - v;
    if (t == 255) *total_out = buf[cur][255];
}

__global__ void k_off(const int* __restrict__ counts, const int* __restrict__ partoff,
                      int* __restrict__ offsets, int* __restrict__ cursor, int N) {
    __shared__ int buf[2][256];
    const int t = threadIdx.x;
    const int i = blockIdx.x * 256 + t;
    int v = (i < N) ? counts[i] : 0;
    buf[0][t] = v;
    __syncthreads();
    int cur = 0;
    for (int d = 1; d < 256; d <<= 1) {
        int x = buf[cur][t];
        if (t >= d) x += buf[cur][t - d];
        buf[cur ^ 1][t] = x;
        cur ^= 1;
        __syncthreads();
    }
    if (i < N) {
        int excl = partoff[blockIdx.x] + buf[cur][t] - v;
        offsets[i] = excl;
        cursor[i]  = excl;
    }
}

__global__ void k_fill_csr(const int* __restrict__ src, const int* __restrict__ dst,
                           const float* __restrict__ eig0, int* __restrict__ cursor,
                           int2* __restrict__ sedge, int E)
{
    int e = blockIdx.x * 256 + threadIdx.x;
    if (e < E) {
        int s = src[e], d = dst[e];
        float w = fabsf(eig0[s] - eig0[d]);
        int pos = atomicAdd(&cursor[d], 1);
        sedge[pos] = make_int2(s, __float_as_int(w));
    }
}

// ---------------- k_agg: gather + aggregate; writes STAGED agg layout ----------------
// (R13 body verbatim — 65us, VGPR 64, no spill. R14's pairwise ACCUM spilled.)
// aggS (bytes): [mt][ks][kg][row][16]  mt=n>>6, row=n&63; lane l16 part p:
//   ks = p*4 + (l16>>2), kg = l16&3.

template<bool PACKED>
__launch_bounds__(256, 4)
__global__ void k_agg(const unsigned* __restrict__ hb,
                      const int2* __restrict__ offcnt, const int* __restrict__ offsets,
                      const unsigned* __restrict__ upk, const int2* __restrict__ sedge,
                      unsigned short* __restrict__ agg, float2* __restrict__ scal, int N)
{
    const int tid = threadIdx.x;
    const int qid = tid >> 4;       // 0..15
    const int l16 = tid & 15;
    const int n = blockIdx.x * 16 + qid;
    if (n >= N) return;

    int e0, cnt;
    if (PACKED) { const int2 oc = offcnt[n]; e0 = oc.x; cnt = oc.y; }
    else        { e0 = offsets[n]; cnt = offsets[n + 1] - e0; }

    const uint4* __restrict__ hb4 = reinterpret_cast<const uint4*>(hb);

    f32x2 s2[4], m2[4], d2[4];
    float wsum = 0.f;
#pragma unroll
    for (int f = 0; f < 4; ++f) {
        s2[f] = (f32x2){0.f, 0.f};
        m2[f] = (f32x2){-INFINITY, -INFINITY};
        d2[f] = (f32x2){0.f, 0.f};
    }
    const int clampi = (cnt > 0) ? cnt - 1 : 0;

    uint4 bufA[8], bufB[8];
    float wvA[8], wvB[8];

#define STAGE(BUF, WV, BASE) do {                                        \
    _Pragma("unroll")                                                    \
    for (int j = 0; j < 8; ++j) {                                        \
        int ci = (BASE) + j; ci = ci < clampi ? ci : clampi;             \
        unsigned sidx;                                                   \
        if (PACKED) {                                                    \
            const unsigned u = upk[e0 + ci];                             \
            WV[j] = __int_as_float(u & 0xffff0000u);                     \
            sidx = (u & 0xffffu) << 4;                                   \
        } else {                                                         \
            const int2 v = sedge[e0 + ci];                               \
            WV[j] = __int_as_float(v.y);                                 \
            sidx = ((unsigned)v.x) << 4;                                 \
        }                                                                \
        BUF[j] = hb4[sidx | (unsigned)l16];                              \
    }                                                                    \
} while (0)

#define ACCUM(BUF, WV, BASE) do {                                        \
    _Pragma("unroll")                                                    \
    for (int j = 0; j < 8; ++j) {                                        \
        if ((BASE) + j < cnt) {                                          \
            const float wj = WV[j];                                      \
            const f32x2 wj2 = (f32x2){wj, wj};                           \
            const f32x2 p0 = up2(BUF[j].x), p1 = up2(BUF[j].y);          \
            const f32x2 p2 = up2(BUF[j].z), p3 = up2(BUF[j].w);          \
            s2[0] += p0; s2[1] += p1; s2[2] += p2; s2[3] += p3;          \
            m2[0].x = fmaxf(m2[0].x, p0.x); m2[0].y = fmaxf(m2[0].y, p0.y); \
            m2[1].x = fmaxf(m2[1].x, p1.x); m2[1].y = fmaxf(m2[1].y, p1.y); \
            m2[2].x = fmaxf(m2[2].x, p2.x); m2[2].y = fmaxf(m2[2].y, p2.y); \
            m2[3].x = fmaxf(m2[3].x, p3.x); m2[3].y = fmaxf(m2[3].y, p3.y); \
            d2[0] += p0 * wj2; d2[1] += p1 * wj2;                        \
            d2[2] += p2 * wj2; d2[3] += p3 * wj2;                        \
            wsum += wj;                                                  \
        }                                                                \
    }                                                                    \
} while (0)

    if (cnt > 0) {
        STAGE(bufA, wvA, 0);
        for (int base = 0; base < cnt; base += 16) {
            const bool haveB = (base + 8) < cnt;
            if (haveB) STAGE(bufB, wvB, base + 8);
            ACCUM(bufA, wvA, base);
            if (base + 16 < cnt) STAGE(bufA, wvA, base + 16);
            if (haveB) ACCUM(bufB, wvB, base + 8);
        }
    }
#undef STAGE
#undef ACCUM

    const float degf = (float)cnt;
    const float inv  = 1.0f / fmaxf(degf, 1.0f);
    const float dinv = 1.0f / (wsum + 1e-30f);
    const bool nz = (cnt > 0);
    uint4 pm, px, pd;
    pm.x = pack2bf(s2[0].x * inv, s2[0].y * inv);
    pm.y = pack2bf(s2[1].x * inv, s2[1].y * inv);
    pm.z = pack2bf(s2[2].x * inv, s2[2].y * inv);
    pm.w = pack2bf(s2[3].x * inv, s2[3].y * inv);
    px.x = pack2bf(nz ? m2[0].x : 0.f, nz ? m2[0].y : 0.f);
    px.y = pack2bf(nz ? m2[1].x : 0.f, nz ? m2[1].y : 0.f);
    px.z = pack2bf(nz ? m2[2].x : 0.f, nz ? m2[2].y : 0.f);
    px.w = pack2bf(nz ? m2[3].x : 0.f, nz ? m2[3].y : 0.f);
    pd.x = pack2bf(d2[0].x * dinv, d2[0].y * dinv);
    pd.y = pack2bf(d2[1].x * dinv, d2[1].y * dinv);
    pd.z = pack2bf(d2[2].x * dinv, d2[2].y * dinv);
    pd.w = pack2bf(d2[3].x * dinv, d2[3].y * dinv);

    uint4* aggv = reinterpret_cast<uint4*>(agg);
    const int mt = n >> 6, row = n & 63;
    const size_t b4 = (size_t)mt * 3072 + (size_t)(l16 & 3) * 64 + row;
    const int kshi = l16 >> 2;                    // ks = p*4 + kshi
    aggv[b4 + (size_t)(0 * 4 + kshi) * 256] = pm; // part 0 (mean)
    aggv[b4 + (size_t)(1 * 4 + kshi) * 256] = px; // part 1 (max)
    aggv[b4 + (size_t)(2 * 4 + kshi) * 256] = pd; // part 2 (dir)
    if (l16 == 0) {
        const float logD = logf(degf + 1.0f);
        scal[n] = make_float2(logD / AVG_D_LOG, AVG_D_LOG / fmaxf(logD, 1e-6f));
    }
}

// ---------------- k_mm: M=128 per block, shared-B staging, coalesced epilogue ----------------
// Two A-tiles share one staged B per K-step: halves Wt traffic, staged bytes, and
// barrier count per output. acc[2][4][2][3] = 96 VGPR; launch_bounds(256,2).

__launch_bounds__(256, 2)
__global__ void k_mm(const unsigned short* __restrict__ agg, const float2* __restrict__ scal,
                     const float* __restrict__ h, const float* __restrict__ snorm,
                     const float* __restrict__ bvec, const float* __restrict__ gam,
                     const float* __restrict__ bet, const float* __restrict__ bmean,
                     const float* __restrict__ bvar, const unsigned short* __restrict__ Wt,
                     float* __restrict__ out, int N, int nT)
{
    __shared__ char smem[33792];                 // As 8K + Bs 24K = 32K; outS 33792 reuses
    unsigned short* As = (unsigned short*)smem;          // [tile2][kg4][row64][16B]
    unsigned short* Bs = (unsigned short*)(smem + 8192);
    float* outS = (float*)smem;

    const int tid  = threadIdx.x;
    const int wave = tid >> 6;
    const int lane = tid & 63;
    const int r16  = lane & 15;
    const int kgrp = lane >> 4;
    const int cb = wave * 32;

    const int mt0 = blockIdx.x * 2;
    const int mt1 = (mt0 + 1 < nT) ? (mt0 + 1) : mt0;
    const char* aggb0 = (const char*)agg + (size_t)mt0 * 49152;
    const char* aggb1 = (const char*)agg + (size_t)mt1 * 49152;
    const char* wtbase = (const char*)Wt;

    auto stage = [&](int ks) {
        GLD16(aggb0 + (size_t)ks * 4096 + wave * 1024 + lane * 16,
              (char*)As + (size_t)wave * 1024);
        GLD16(aggb1 + (size_t)ks * 4096 + wave * 1024 + lane * 16,
              (char*)As + (size_t)(4 + wave) * 1024);
#pragma unroll
        for (int i = 0; i < 6; ++i) {
            const int c = wave * 6 + i;
            GLD16(wtbase + (size_t)ks * 24576 + (size_t)c * 1024 + lane * 16,
                  (char*)Bs + (size_t)c * 1024);
        }
    };

    f32x4 acc[2][4][2][3];
#pragma unroll
    for (int t = 0; t < 2; ++t)
#pragma unroll
        for (int m = 0; m < 4; ++m)
#pragma unroll
            for (int ct = 0; ct < 2; ++ct)
#pragma unroll
                for (int sv = 0; sv < 3; ++sv)
                    acc[t][m][ct][sv] = (f32x4){0.f, 0.f, 0.f, 0.f};

    for (int ks = 0; ks < 12; ++ks) {
        if (ks) __syncthreads();            // prev step's LDS reads done
        stage(ks);
        __syncthreads();                    // vmcnt drained: staged data ready

        bf16x8 a0[4], a1[4], b[6];
#pragma unroll
        for (int m = 0; m < 4; ++m) {
            a0[m] = *reinterpret_cast<const bf16x8*>(
                &As[((size_t)kgrp * 64 + m * 16 + r16) * 8]);
            a1[m] = *reinterpret_cast<const bf16x8*>(
                &As[((size_t)(4 + kgrp) * 64 + m * 16 + r16) * 8]);
        }
#pragma unroll
        for (int sv = 0; sv < 3; ++sv)
#pragma unroll
            for (int ct = 0; ct < 2; ++ct)
                b[sv * 2 + ct] = *reinterpret_cast<const bf16x8*>(
                    &Bs[(((size_t)sv * 4 + kgrp) * 128 + cb + ct * 16 + r16) * 8]);
#pragma unroll
        for (int sv = 0; sv < 3; ++sv)
#pragma unroll
            for (int ct = 0; ct < 2; ++ct)
#pragma unroll
                for (int m = 0; m < 4; ++m) {
                    acc[0][m][ct][sv] = __builtin_amdgcn_mfma_f32_16x16x32_bf16(
                        a0[m], b[sv * 2 + ct], acc[0][m][ct][sv], 0, 0, 0);
                    acc[1][m][ct][sv] = __builtin_amdgcn_mfma_f32_16x16x32_bf16(
                        a1[m], b[sv * 2 + ct], acc[1][m][ct][sv], 0, 0, 0);
                }
    }

    // ---- epilogue: per tile, park y in LDS then coalesced residual+store ----
    __syncthreads();                        // all waves done reading As/Bs
#pragma unroll
    for (int t = 0; t < 2; ++t) {
        if (t == 1 && mt1 == mt0) break;
        const int nb = (t ? mt1 : mt0) * 64;
#pragma unroll
        for (int ct = 0; ct < 2; ++ct) {
            const int col = cb + ct * 16 + r16;
            const float bc  = bvec[col];
            const float mc  = bmean[col];
            const float rs  = rsqrtf(bvar[col] + BN_EPS);
            const float gc  = gam[col];
            const float bec = bet[col];
#pragma unroll
            for (int m = 0; m < 4; ++m) {
#pragma unroll
                for (int r = 0; r < 4; ++r) {
                    const int row = m * 16 + kgrp * 4 + r;
                    const int n  = nb + row;
                    float sn = 0.f; float2 sc = make_float2(0.f, 0.f);
                    if (n < N) { sn = snorm[n]; sc = scal[n]; }
                    float v = acc[t][m][ct][0][r] + sc.x * acc[t][m][ct][1][r]
                                                  + sc.y * acc[t][m][ct][2][r];
                    float y = (v + bc) * sn;
                    y = (y - mc) * rs * gc + bec;
                    y = fmaxf(y, 0.f);
                    outS[row * 132 + col] = y;
                }
            }
        }
        __syncthreads();
        const int rows = (N - nb < 64) ? (N - nb) : 64;
#pragma unroll
        for (int it = 0; it < 8; ++it) {
            const int idx = it * 256 + tid;     // [0, 2048) float4 slots
            const int row = idx >> 5;
            const int c4  = idx & 31;
            if (row < rows) {
                const float4 hv = *reinterpret_cast<const float4*>(
                    &h[(size_t)(nb + row) * 128 + c4 * 4]);
                float4 yv = *reinterpret_cast<const float4*>(&outS[row * 132 + c4 * 4]);
                yv.x += hv.x; yv.y += hv.y; yv.z += hv.z; yv.w += hv.w;
                *reinterpret_cast<float4*>(&out[(size_t)(nb + row) * 128 + c4 * 4]) = yv;
            }
        }
        __syncthreads();                    // before next tile overwrites outS
    }
}

// ---------------- launch ----------------

extern "C" void kernel_launch(void* const* d_in, const int* in_sizes, int n_in,
                              void* d_out, int out_size, void* d_ws, size_t ws_size,
                              hipStream_t stream)
{
    const float* h     = (const float*)d_in[0];
    const float* eig   = (const float*)d_in[1];
    const float* snorm = (const float*)d_in[2];
    const float* W     = (const float*)d_in[3];
    const float* bvec  = (const float*)d_in[4];
    const float* gam   = (const float*)d_in[5];
    const float* bet   = (const float*)d_in[6];
    const float* bmean = (const float*)d_in[7];
    const float* bvar  = (const float*)d_in[8];
    const int*   esrc  = (const int*)d_in[9];
    const int*   edst  = (const int*)d_in[10];
    float* out = (float*)d_out;

    const int N = in_sizes[0] / DIN;
    const int E = in_sizes[9];
    const int NB = (N + 255) / 256;
    const int nPairs = N * DIN / 2;
    const int wTotal = 3 * 128 * 384;
    const int nbk = (N + 127) >> BSH;
    const int N64 = (N + 63) / 64;
    const int N128 = (N + 127) / 128;
    (void)ws_size; (void)n_in; (void)out_size;

    char* base = (char*)d_ws;
    size_t o = 0;
    auto take = [&](size_t bytes) {
        char* p = base + o;
        o = (o + bytes + 255) & ~(size_t)255;
        return p;
    };
    // common scratch
    unsigned* hb       = (unsigned*)take((size_t)nPairs * 4);
    unsigned short* Wt = (unsigned short*)take((size_t)wTotal * 2);
    float* eig0        = (float*)take((size_t)N * 4);
    int* cursor        = (int*)take((size_t)(N + 1) * 4);
    float2* scal       = (float2*)take((size_t)N * 8);

    const size_t agg_bytes  = (size_t)N64 * 49152;   // staged [mt][ks][kg][row][16]
    const size_t stag_bytes = (size_t)nbk * BCAP * 8;
    const size_t shared_bytes = agg_bytes > stag_bytes ? agg_bytes : stag_bytes;

    const size_t bucket_bytes = (size_t)nbk * BCAP * 4
                              + (size_t)N * 8
                              + (size_t)nbk * 4
                              + shared_bytes + 8192;
    const bool bucketOK = (N <= 65536) && (nbk <= 512) && ((o + bucket_bytes) <= ws_size);

    const int gridPrep = (nPairs + 255) / 256;
    const int gridE    = (E + 255) / 256;
    const int gridB    = (E + 256 * ITEMS - 1) / (256 * ITEMS);
    const int gridN16  = (N + 15) / 16;

    if (bucketOK) {
        unsigned* fin   = (unsigned*)take((size_t)nbk * BCAP * 4);
        int2* offcnt    = (int2*)take((size_t)N * 8);
        int* bcur       = (int*)take((size_t)nbk * 4);
        char* shared    = take(shared_bytes);
        uint2* stag     = (uint2*)shared;                 // dead after k_group
        unsigned short* agg = (unsigned short*)shared;    // written by k_agg

        k_prep<<<gridPrep, 256, 0, stream>>>(h, hb, W, Wt, eig, eig0, cursor, bcur,
                                             nPairs, wTotal, N, nbk);
        k_bucket<<<gridB, 256, 0, stream>>>(esrc, edst, eig0, bcur, stag, E, nbk);
        k_group<<<nbk, 256, 0, stream>>>(bcur, stag, fin, offcnt, N);
        k_agg<true><<<gridN16, 256, 0, stream>>>(hb, offcnt, nullptr, fin, nullptr,
                                                 agg, scal, N);
        k_mm<<<N128, 256, 0, stream>>>(agg, scal, h, snorm, bvec, gam, bet, bmean, bvar,
                                       Wt, out, N, N64);
    } else {
        int* counts  = (int*)take((size_t)(N + 1) * 4);
        int* offsets = (int*)take((size_t)(N + 1) * 4);
        int2* sedge  = (int2*)take((size_t)(E + 16) * 8);
        int* part    = (int*)take((size_t)NB * 4);
        int* partoff = (int*)take((size_t)NB * 4);
        int* bcur    = (int*)take(4096);
        unsigned short* agg = (unsigned short*)take(agg_bytes);

        k_prep<<<gridPrep, 256, 0, stream>>>(h, hb, W, Wt, eig, eig0, counts, bcur,
                                             nPairs, wTotal, N, 1);
        k_hist<<<gridE, 256, 0, stream>>>(edst, counts, E);
        k_part<<<NB, 256, 0, stream>>>(counts, part, N);
        k_scan1<<<1, 256, 0, stream>>>(part, partoff, &offsets[N], NB);
        k_off<<<NB, 256, 0, stream>>>(counts, partoff, offsets, cursor, N);
        k_fill_csr<<<gridE, 256, 0, stream>>>(esrc, edst, eig0, cursor, sedge, E);
        k_agg<false><<<gridN16, 256, 0, stream>>>(hb, nullptr, offsets, nullptr, sedge,
                                                  agg, scal, N);
        k_mm<<<N128, 256, 0, stream>>>(agg, scal, h, snorm, bvec, gam, bet, bmean, bvar,
                                       Wt, out, N, N64);
    }
}